// Round 7
// baseline (102.866 us; speedup 1.0000x reference)
//
#include <hip/hip_runtime.h>

#define BB 8
#define NN 4096
#define NPTS (2*BB*NN)            // 65536 packed points
#define GMIN_OFF (1 << 20)        // gmin[] lives 1 MB into ws (past pk)
#define RPT 8                     // rows per thread
#define ROWS 512                  // rows per block (64 lanes * RPT)
#define WVS 16                    // waves per block
#define JC 2                      // j-chunks (cross-block combine via gmin)
#define JCHUNK (NN/JC)            // 2048 targets staged per block
#define JSL (JCHUNK/WVS)          // 128 targets per wave-slice
#define TOTROWS (2*BB*NN)         // 65536

// Pre-pack both clouds as (x, y, z, 0.5*|p|^2) float4 -> ws.
__global__ __launch_bounds__(256) void cd_pack(const float* __restrict__ src,
                                               const float* __restrict__ tgt,
                                               float4* __restrict__ pk) {
    int i = blockIdx.x * 256 + threadIdx.x;      // 0..65535
    const float* p = ((i >> 15) ? tgt : src) + 3 * (i & 32767);
    float x = p[0], y = p[1], z = p[2];
    pk[i] = make_float4(x, y, z, 0.5f * (x*x + y*y + z*z));
}

// Block = (dir, batch, rowgroup, jc). 1024 thr = 16 waves = 4/SIMD at 1 blk/CU.
// Targets staged in LDS; wave w reads its slice via SINGLE-ADDRESS (wave-
// uniform) ds_read_b128 broadcasts (~12 pipe-cyc each). RPT=8 rows/thread
// gives 32 VALU instr per target per wave (64 SIMD-cyc) -> VALU-bound
// (per CU per round: LDS 16x12=192 cyc < VALU 4x64=256 cyc per SIMD).
// Inner math: acc = 0.5|t|^2 - <s,t> (3 fma) + min; row-constant 0.5|s|^2
// folded after the j-loop (min is shift-invariant).
__global__ __launch_bounds__(1024) void cd_scan(const float4* __restrict__ pk,
                                                float* __restrict__ gmin) {
    __shared__ float4 tl[JCHUNK];    // 32 KB staged targets
    __shared__ float pm[WVS][ROWS];  // 32 KB per-slice row mins (q folded)
    const int dir = blockIdx.z;
    const int b   = blockIdx.y;
    const int rt  = blockIdx.x >> 1;             // rowgroup 0..7
    const int jc  = blockIdx.x & 1;
    const int tid = threadIdx.x, lane = tid & 63, wave = tid >> 6;   // 0..15

    const float4* S = pk + (dir ? (size_t)BB*NN : 0) + (size_t)b*NN;
    const float4* T = pk + (dir ? 0 : (size_t)BB*NN) + (size_t)b*NN + (size_t)jc*JCHUNK;

    // Stage this block's 2048-target chunk (coalesced dwordx4).
    tl[tid]        = T[tid];
    tl[tid + 1024] = T[tid + 1024];

    // 8 source rows per thread (same rows for every wave; L2-hot).
    float nx[RPT], ny[RPT], nz[RPT], q[RPT];
#pragma unroll
    for (int r = 0; r < RPT; ++r) {
        float4 s = S[rt*ROWS + r*64 + lane];
        nx[r] = -s.x; ny[r] = -s.y; nz[r] = -s.z; q[r] = s.w;
    }
    __syncthreads();

    const int jofs = wave * JSL;                 // wave-uniform slice base
    float m[RPT];
#pragma unroll
    for (int r = 0; r < RPT; ++r) m[r] = 1.0e30f;

    for (int j = 0; j < JSL; j += 4) {
        float4 t0 = tl[jofs + j];                // single-address broadcasts
        float4 t1 = tl[jofs + j + 1];
        float4 t2 = tl[jofs + j + 2];
        float4 t3 = tl[jofs + j + 3];
#pragma unroll
        for (int r = 0; r < RPT; ++r) {
            float a0 = fmaf(nx[r], t0.x, fmaf(ny[r], t0.y, fmaf(nz[r], t0.z, t0.w)));
            float a1 = fmaf(nx[r], t1.x, fmaf(ny[r], t1.y, fmaf(nz[r], t1.z, t1.w)));
            float a2 = fmaf(nx[r], t2.x, fmaf(ny[r], t2.y, fmaf(nz[r], t2.z, t2.w)));
            float a3 = fmaf(nx[r], t3.x, fmaf(ny[r], t3.y, fmaf(nz[r], t3.z, t3.w)));
            m[r] = fminf(m[r], fminf(fminf(a0, a1), fminf(a2, a3)));
        }
    }

#pragma unroll
    for (int r = 0; r < RPT; ++r)
        pm[wave][r*64 + lane] = m[r] + q[r];     // full d^2/2 for this slice
    __syncthreads();

    // Threads 0..511: combine 16 slice-partials for row `tid`, write global.
    if (tid < ROWS) {
        float v = pm[0][tid];
#pragma unroll
        for (int s = 1; s < WVS; ++s) v = fminf(v, pm[s][tid]);
        gmin[(size_t)jc*TOTROWS + ((size_t)dir*BB + b)*NN + rt*ROWS + tid] = v;
    }
}

// Combine the two j-chunks per row, sqrt, and reduce to the scalar loss.
__global__ __launch_bounds__(1024) void cd_final(const float* __restrict__ gmin,
                                                 float* __restrict__ out) {
    __shared__ float ps[16];
    float sum = 0.0f;
    for (int i = threadIdx.x; i < TOTROWS; i += 1024) {
        float v = fminf(gmin[i], gmin[TOTROWS + i]);
        v = fmaxf(v, 0.0f);          // clamp fp rounding negatives
        sum += sqrtf(2.0f * v);
    }
#pragma unroll
    for (int o = 32; o > 0; o >>= 1) sum += __shfl_down(sum, o, 64);
    if ((threadIdx.x & 63) == 0) ps[threadIdx.x >> 6] = sum;
    __syncthreads();
    if (threadIdx.x == 0) {
        float t = 0.0f;
#pragma unroll
        for (int w = 0; w < 16; ++w) t += ps[w];
        out[0] = t * (1.0f / (float)(BB * NN));  // mean(term1) + mean(term2)
    }
}

extern "C" void kernel_launch(void* const* d_in, const int* in_sizes, int n_in,
                              void* d_out, int out_size, void* d_ws, size_t ws_size,
                              hipStream_t stream) {
    const float* src = (const float*)d_in[0];
    const float* tgt = (const float*)d_in[1];
    float4* pk = (float4*)d_ws;                            // 1 MB
    float* gmin = (float*)((char*)d_ws + GMIN_OFF);        // 2 x 65536 floats
    float* out = (float*)d_out;

    cd_pack<<<NPTS / 256, 256, 0, stream>>>(src, tgt, pk);
    dim3 grid((NN / ROWS) * JC, BB, 2);                    // 16 x 8 x 2 = 256
    cd_scan<<<grid, 1024, 0, stream>>>(pk, gmin);
    cd_final<<<1, 1024, 0, stream>>>(gmin, out);
}